// Round 5
// baseline (197.624 us; speedup 1.0000x reference)
//
#include <hip/hip_runtime.h>
#include <hip/hip_bf16.h>

// Shapes: B=512, BAG=32, H=1024, C=53.  EPS=1e-8, scale=sqrt(1024)=32.
// Out: bag_out (512*53=27136) f32, then cl_loss scalar -> 27137 floats.

typedef __bf16 bf16x8 __attribute__((ext_vector_type(8)));
typedef __bf16 bf16x4 __attribute__((ext_vector_type(4)));
typedef __bf16 bf16x2 __attribute__((ext_vector_type(2)));
typedef float  f32x4  __attribute__((ext_vector_type(4)));

__device__ inline float wsum(float v) {
    #pragma unroll
    for (int off = 32; off > 0; off >>= 1) v += __shfl_xor(v, off, 64);
    return v;
}

__device__ inline void gll16(const void* g, void* l) {
    __builtin_amdgcn_global_load_lds((const __attribute__((address_space(1))) void*)g,
                                     (__attribute__((address_space(3))) void*)l, 16, 0, 0);
}

__device__ inline f32x4 ntld(const float* p) {
    return __builtin_nontemporal_load((const f32x4*)p);
}

// ---- kab: merged streaming pass + per-bag softmax/bag (one bag per block) ----
__global__ __launch_bounds__(512, 4) void kab(
    const float* __restrict__ sent, const float* __restrict__ aug,
    const float* __restrict__ rel_table, const int* __restrict__ labels,
    __bf16* __restrict__ repb, float* __restrict__ nr, float* __restrict__ pos_sim,
    const float* __restrict__ clsw, __bf16* __restrict__ cwb,
    __bf16* __restrict__ bagb, float* __restrict__ nbsq, float* __restrict__ loss)
{
    __shared__ __align__(16) __bf16 repS[32][1024];    // 64 KB
    __shared__ float scoreS[32], alphaS[32], redS[8];
    const int b = blockIdx.x, t = threadIdx.x;
    const int w = t >> 6, lane = t & 63;

    // folded k0: blocks 0..127 convert cls_w (padded to 64 rows); block 0 zeroes loss
    if (b < 128) {
        const int i = b * 512 + t;
        cwb[i] = (i < 53 * 1024) ? (__bf16)clsw[i] : (__bf16)0.0f;
        if (b == 0 && t == 0) *loss = 0.0f;
    }

    const float* relp = rel_table + (size_t)labels[b] * 1024;
    #pragma unroll
    for (int rr = 0; rr < 4; rr++) {
        const int j = w * 4 + rr;                      // row within bag
        const size_t rbase = ((size_t)b * 32 + j) * 1024;
        const float* srow = sent + rbase;
        const float* arow = aug + rbase;
        float P = 0.f, R = 0.f, A = 0.f, D = 0.f;
        #pragma unroll
        for (int i = 0; i < 4; i++) {
            const int h = i * 256 + lane * 4;
            f32x4 v  = ntld(srow + h);                 // nt: read-once
            f32x4 a  = ntld(arow + h);
            f32x4 rl = *(const f32x4*)(relp + h);      // L1-hot across rows
            P += v.x * rl.x + v.y * rl.y + v.z * rl.z + v.w * rl.w;
            R += v.x * v.x + v.y * v.y + v.z * v.z + v.w * v.w;
            A += a.x * a.x + a.y * a.y + a.z * a.z + a.w * a.w;
            D += v.x * a.x + v.y * a.y + v.z * a.z + v.w * a.w;
            bf16x4 vb = { (__bf16)v.x, (__bf16)v.y, (__bf16)v.z, (__bf16)v.w };
            *(bf16x4*)(&repS[j][h]) = vb;
            *(bf16x4*)(repb + rbase + h) = vb;
        }
        #pragma unroll
        for (int off = 32; off > 0; off >>= 1) {
            P += __shfl_xor(P, off, 64);
            R += __shfl_xor(R, off, 64);
            A += __shfl_xor(A, off, 64);
            D += __shfl_xor(D, off, 64);
        }
        if (lane == 0) {
            scoreS[j] = P * (1.0f / 32.0f);            // /sqrt(H)
            float nrv = sqrtf(R), nav = sqrtf(A);
            nr[b * 32 + j] = nrv;
            pos_sim[b * 32 + j] = D / fmaxf(nrv * nav, 1e-8f);
        }
    }
    __syncthreads();

    if (t < 32) {
        float sj = scoreS[t], mx = sj;
        #pragma unroll
        for (int off = 16; off > 0; off >>= 1) mx = fmaxf(mx, __shfl_xor(mx, off, 32));
        float e = __expf(sj - mx), sm = e;
        #pragma unroll
        for (int off = 16; off > 0; off >>= 1) sm += __shfl_xor(sm, off, 32);
        alphaS[t] = e / sm;
    }
    __syncthreads();

    float b0 = 0.f, b1 = 0.f;
    #pragma unroll 8
    for (int j = 0; j < 32; j++) {
        const float al = alphaS[j];
        bf16x2 v = *(const bf16x2*)(&repS[j][t * 2]);
        b0 += al * (float)v.x;
        b1 += al * (float)v.y;
    }
    bf16x2 bb = { (__bf16)b0, (__bf16)b1 };
    *(bf16x2*)(bagb + (size_t)b * 1024 + t * 2) = bb;

    float q = b0 * b0 + b1 * b1;
    q = wsum(q);
    if (lane == 0) redS[w] = q;
    __syncthreads();
    if (t == 0)
        nbsq[b] = redS[0] + redS[1] + redS[2] + redS[3]
                + redS[4] + redS[5] + redS[6] + redS[7];
}

// ---- k4: MFMA 256x128 tile, 8 waves of 64x64, BK=32, 4-buf depth-2 pipeline ----
// LDS-BW is the binding pipe (measured ~85 B/cy/CU for b128 streams). Per step:
//   old 128x128/64x32-waves: 32KB wr + 96KB rd = 128KB/CU  (~1500 cy/step)
//   new 256x128/64x64-waves: 24KB wr + 64KB rd =  88KB/CU  (~1035 cy/step)
// Grid: 64 rb x 4 cb = 256 GEMM blocks (1/CU) + 8 classifier blocks.
// Buffers: 4 x 24KB (A 16KB | B 8KB), step s at smem + (s&3)*24576.
// Stage s+3 while computing s; 3 gll16/thread/step; FENCE(6) keeps the 2 newest
// steps in flight. Swizzle: slot (row,kg') holds cols 8*(kg'^rho(row)),
// rho=(row>>1)&3; staging source pre-swizzled per-lane (4 lanes cover one 64B
// segment -> coalesced); gll16 dest linear; fragment reads 2-way bank = free.
// Epilogue: per-wave 2-bag merge -> negp4[4][32][128] overlay (each slot written
// exactly once, no races) -> cross-wave sum -> partial[64rb][32][512] (4MB).
__global__ __launch_bounds__(512, 2) void k4_gemm(
    const __bf16* __restrict__ repb, const __bf16* __restrict__ bagb,
    const float* __restrict__ nr, const float* __restrict__ nbsq,
    const float* __restrict__ temp, float* __restrict__ partial, float* __restrict__ diag,
    const __bf16* __restrict__ cwb, const float* __restrict__ bias, float* __restrict__ out)
{
    __shared__ __align__(16) char smem[98304];         // 4 x 24KB bufs; negp4 overlays
    const int bid = blockIdx.x;
    const int t = threadIdx.x, lane = t & 63, w = t >> 6;
    const int m = lane & 15, quad = lane >> 4;

    if (bid >= 256) {
        // ---- folded k3m: bag_out = bagb @ cwb^T + cls_b (t<256 active) ----
        __bf16* Al = (__bf16*)smem;
        __bf16* Bl = (__bf16*)(smem + 8192);
        const int r0 = (bid - 256) * 64;
        f32x4 acc[4] = {};
        const int i0 = (t & 255) * 8;
        const int row0 = i0 >> 5, kk0 = i0 & 31;
        const __bf16* gA = bagb + (size_t)(r0 + row0) * 1024 + kk0;
        const __bf16* gB = cwb + (size_t)row0 * 1024 + kk0;
        const bool act = (t < 256);
        for (int k0 = 0; k0 < 1024; k0 += 64) {
            __syncthreads();
            if (act) {
                gll16(gA + k0,      Al + i0);
                gll16(gA + k0 + 32, Al + 2048 + i0);
                gll16(gB + k0,      Bl + i0);
                gll16(gB + k0 + 32, Bl + 2048 + i0);
            }
            __syncthreads();
            if (act) {
                #pragma unroll
                for (int ks = 0; ks < 2; ks++) {
                    bf16x8 a = *(const bf16x8*)(&Al[ks * 2048 + ((t >> 6) * 16 + m) * 32 + quad * 8]);
                    #pragma unroll
                    for (int n = 0; n < 4; n++) {
                        bf16x8 bf = *(const bf16x8*)(&Bl[ks * 2048 + (n * 16 + m) * 32 + quad * 8]);
                        acc[n] = __builtin_amdgcn_mfma_f32_16x16x32_bf16(a, bf, acc[n], 0, 0, 0);
                    }
                }
            }
        }
        if (act) {
            #pragma unroll
            for (int n = 0; n < 4; n++) {
                const int c = n * 16 + m;
                if (c < 53) {
                    #pragma unroll
                    for (int i = 0; i < 4; i++) {
                        const int r = r0 + (t >> 6) * 16 + quad * 4 + i;
                        out[(size_t)r * 53 + c] = acc[n][i] + bias[c];
                    }
                }
            }
        }
        return;
    }

    float* negp4 = (float*)smem;                       // [4][32][128] f32 = 64KB overlay

    const int xcd = bid & 7, slot = bid >> 3;
    const int cb = slot & 3, rb = (slot >> 2) * 8 + xcd;   // rb 0..63, cb 0..3
    const int r0 = rb * 256, c0 = cb * 128;
    const int wr0 = (w & 3) * 64, wc0 = (w >> 2) * 64;     // wave = 64x64

    // staging: thread t -> A slots {t, t+512}, B slot {t} (3 gll16/step)
    const int srow = t >> 2;                           // 0..127
    const int scol = 8 * ((t & 3) ^ ((t >> 3) & 3));   // swizzled 16B k-group
    const __bf16* gA0 = repb + (size_t)(r0 + srow) * 1024 + scol;
    const __bf16* gA1 = gA0 + (size_t)128 * 1024;      // rows +128 (same swizzle)
    const __bf16* gB0 = bagb + (size_t)(c0 + srow) * 1024 + scol;
    const int dA0 = t * 8, dA1 = (t + 512) * 8, dB0 = 8192 + t * 8;  // bf16 units

    // fragment-read offsets (bf16 units); rho depends only on m (wr0,wc0 mult 64)
    const int rho = (m >> 1) & 3;
    const int offA = ((wr0 + m) * 4 + (quad ^ rho)) * 8;
    const int offB = 8192 + ((wc0 + m) * 4 + (quad ^ rho)) * 8;

    f32x4 acc[4][4] = {};

    #define BUFB(s) ((__bf16*)(smem + (((s) & 3) * 24576)))
    #define STG(s) do { const int kk_ = (s) * 32; __bf16* b_ = BUFB(s);     \
        gll16(gA0 + kk_, b_ + dA0); gll16(gA1 + kk_, b_ + dA1);             \
        gll16(gB0 + kk_, b_ + dB0); } while (0)

    #define CMP(s) do { const __bf16* b_ = BUFB(s); bf16x8 av_[4], bv_[4];  \
        _Pragma("unroll") for (int i_ = 0; i_ < 4; i_++)                    \
            av_[i_] = *(const bf16x8*)(b_ + offA + i_ * 512);               \
        _Pragma("unroll") for (int n_ = 0; n_ < 4; n_++)                    \
            bv_[n_] = *(const bf16x8*)(b_ + offB + n_ * 512);               \
        _Pragma("unroll") for (int i_ = 0; i_ < 4; i_++)                    \
        _Pragma("unroll") for (int n_ = 0; n_ < 4; n_++)                    \
            acc[i_][n_] = __builtin_amdgcn_mfma_f32_16x16x32_bf16(          \
                av_[i_], bv_[n_], acc[i_][n_], 0, 0, 0); } while (0)

    #define FENCE(N) do { __builtin_amdgcn_sched_barrier(0);                \
        asm volatile("s_waitcnt vmcnt(" #N ")" ::: "memory");               \
        __builtin_amdgcn_s_barrier();                                       \
        __builtin_amdgcn_sched_barrier(0); } while (0)

    STG(0); STG(1); STG(2);
    FENCE(6);                                   // step 0 resident; 1,2 in flight
    #pragma unroll 1
    for (int s = 0; s < 29; ++s) {              // stage s+3, compute s
        STG(s + 3);
        CMP(s);
        FENCE(6);                               // retire s+1; keep s+2,s+3 flying
    }
    CMP(29); FENCE(3);                          // retire step 30
    CMP(30); FENCE(0);                          // retire step 31 (barrier: buf reads of 0..2 done)
    CMP(31);                                    // reads buf 3 only (disjoint from negp4)

    const float invT = 1.0f / *temp;
    float nrv[16];
    #pragma unroll
    for (int i = 0; i < 4; i++)
        #pragma unroll
        for (int g = 0; g < 4; g++)
            nrv[i * 4 + g] = nr[r0 + wr0 + i * 16 + quad * 4 + g];

    // per-wave 2-bag merge into negp4[w&3][jj][c_local]; every slot written once
    float* myneg = negp4 + (size_t)(w & 3) * 32 * 128;
    #pragma unroll
    for (int n = 0; n < 4; n++) {
        const int c_local = wc0 + n * 16 + m;
        const int cg = c0 + c_local;
        const float nbv = sqrtf(nbsq[cg]);
        #pragma unroll
        for (int i = 0; i < 2; i++) {                  // bag pairs (i, i+2)
            #pragma unroll
            for (int g = 0; g < 4; g++) {
                const int jj = i * 16 + quad * 4 + g;
                const int rg0 = r0 + wr0 + i * 16 + quad * 4 + g;
                const int rg2 = rg0 + 32;
                float e0 = __expf(acc[i][n][g]     / fmaxf(nbv * nrv[i * 4 + g],       1e-8f) * invT);
                float e2 = __expf(acc[i + 2][n][g] / fmaxf(nbv * nrv[(i + 2) * 4 + g], 1e-8f) * invT);
                myneg[jj * 128 + c_local] = e0 + e2;
                if ((rg0 >> 5) == cg) diag[(size_t)cg * 32 + jj] = e0;
                if ((rg2 >> 5) == cg) diag[(size_t)cg * 32 + jj] = e2;
            }
        }
    }
    __syncthreads();

    // cross-wave reduce (4 wr-groups) + write partial[rb][jj][c0..c0+127]
    float* pout = partial + (size_t)rb * 32 * 512 + c0;
    {
        const int jj = t >> 4, c8 = (t & 15) * 8;      // 512 thr x 8 = 4096 outs
        f32x4 v0 = {}, v1 = {};
        #pragma unroll
        for (int p = 0; p < 4; p++) {
            const float* src = negp4 + (size_t)p * 32 * 128 + jj * 128 + c8;
            v0 += *(const f32x4*)(src);
            v1 += *(const f32x4*)(src + 4);
        }
        *(f32x4*)(pout + (size_t)jj * 512 + c8)     = v0;
        *(f32x4*)(pout + (size_t)jj * 512 + c8 + 4) = v1;
    }
    #undef BUFB
    #undef STG
    #undef CMP
    #undef FENCE
}

// ---- k5: reduce partial over rb (64) + loss terms; atomic accumulate into loss ----
__global__ __launch_bounds__(256) void k5_neg(
    const float* __restrict__ partial, const float* __restrict__ diag,
    const float* __restrict__ pos_sim, const float* __restrict__ temp,
    float* __restrict__ loss)
{
    const int ct = blockIdx.x & 7, j = blockIdx.x >> 3;
    const int t = threadIdx.x, lane = t & 63, w = t >> 6;
    const int bsub = t >> 4;                           // 0..15 (rb-group of 4)
    const int cidx = t & 15;                           // x4 cols
    f32x4 acc = {};
    #pragma unroll
    for (int r = 0; r < 4; r++) {
        const int rb = bsub * 4 + r;
        f32x4 v = *(const f32x4*)(partial + ((size_t)rb * 32 + j) * 512 + ct * 64 + cidx * 4);
        acc += v;
    }
    #pragma unroll
    for (int k = 0; k < 4; k++) {
        acc[k] += __shfl_xor(acc[k], 16, 64);
        acc[k] += __shfl_xor(acc[k], 32, 64);
    }
    __shared__ float red[4][64];
    if (lane < 16) {
        #pragma unroll
        for (int k = 0; k < 4; k++) red[w][lane * 4 + k] = acc[k];
    }
    __syncthreads();

    if (t < 64) {
        const int c = ct * 64 + t;
        float S = red[0][t] + red[1][t] + red[2][t] + red[3][t];
        S -= diag[(size_t)c * 32 + j];                 // near-exact cancellation (f32)
        const float invT = 1.0f / *temp;
        const float lp = pos_sim[(c << 5) + j] * invT;
        float term = logf(__expf(lp) + S) - lp;
        term = wsum(term);
        if (t == 0) atomicAdd(loss, term * (1.0f / 16384.0f));
    }
}

extern "C" void kernel_launch(void* const* d_in, const int* in_sizes, int n_in,
                              void* d_out, int out_size, void* d_ws, size_t ws_size,
                              hipStream_t stream)
{
    const float* sent = (const float*)d_in[0];
    const float* aug  = (const float*)d_in[1];
    const float* rel  = (const float*)d_in[2];
    const float* clsw = (const float*)d_in[3];
    const float* clsb = (const float*)d_in[4];
    const int*   lab  = (const int*)d_in[5];
    const float* temp = (const float*)d_in[6];
    float* out = (float*)d_out;

    char* ws = (char*)d_ws;
    __bf16* bagb    = (__bf16*)(ws);                           // 1 MB
    float*  nbsq    = (float*)(ws + (1u << 20));               // 2 KB
    float*  nr      = (float*)(ws + (1u << 20) + 64 * 1024);   // 64 KB
    float*  pos     = (float*)(ws + (1u << 20) + 128 * 1024);  // 64 KB
    __bf16* cwb     = (__bf16*)(ws + (1u << 20) + 192 * 1024); // 128 KB
    float*  diag    = (float*)(ws + (2u << 20) + 64 * 1024);   // 64 KB
    __bf16* repb    = (__bf16*)(ws + (4u << 20));              // 32 MB
    float*  partial = (float*)(ws + (36u << 20));              // 4 MB (64 rb)

    float* loss = out + 27136;

    kab    <<<512, 512, 0, stream>>>(sent, aug, rel, lab, repb, nr, pos,
                                     clsw, cwb, bagb, nbsq, loss);
    k4_gemm<<<264, 512, 0, stream>>>(repb, bagb, nr, nbsq, temp, partial, diag,
                                     cwb, clsb, out);
    k5_neg <<<256, 256, 0, stream>>>(partial, diag, pos, temp, loss);
}

// Round 6
// 189.752 us; speedup vs baseline: 1.0415x; 1.0415x over previous
//
#include <hip/hip_runtime.h>
#include <hip/hip_bf16.h>

// Shapes: B=512, BAG=32, H=1024, C=53.  EPS=1e-8, scale=sqrt(1024)=32.
// Out: bag_out (512*53=27136) f32, then cl_loss scalar -> 27137 floats.

typedef __bf16 bf16x8 __attribute__((ext_vector_type(8)));
typedef __bf16 bf16x4 __attribute__((ext_vector_type(4)));
typedef __bf16 bf16x2 __attribute__((ext_vector_type(2)));
typedef float  f32x4  __attribute__((ext_vector_type(4)));

__device__ inline float wsum(float v) {
    #pragma unroll
    for (int off = 32; off > 0; off >>= 1) v += __shfl_xor(v, off, 64);
    return v;
}

__device__ inline void gll16(const void* g, void* l) {
    __builtin_amdgcn_global_load_lds((const __attribute__((address_space(1))) void*)g,
                                     (__attribute__((address_space(3))) void*)l, 16, 0, 0);
}

__device__ inline f32x4 ntld(const float* p) {
    return __builtin_nontemporal_load((const f32x4*)p);
}

// ---- kab: merged streaming pass + per-bag softmax/bag (one bag per block) ----
__global__ __launch_bounds__(512, 4) void kab(
    const float* __restrict__ sent, const float* __restrict__ aug,
    const float* __restrict__ rel_table, const int* __restrict__ labels,
    __bf16* __restrict__ repb, float* __restrict__ nr, float* __restrict__ pos_sim,
    const float* __restrict__ clsw, __bf16* __restrict__ cwb,
    __bf16* __restrict__ bagb, float* __restrict__ nbsq, float* __restrict__ loss)
{
    __shared__ __align__(16) __bf16 repS[32][1024];    // 64 KB
    __shared__ float scoreS[32], alphaS[32], redS[8];
    const int b = blockIdx.x, t = threadIdx.x;
    const int w = t >> 6, lane = t & 63;

    // folded k0: blocks 0..127 convert cls_w (padded to 64 rows); block 0 zeroes loss
    if (b < 128) {
        const int i = b * 512 + t;
        cwb[i] = (i < 53 * 1024) ? (__bf16)clsw[i] : (__bf16)0.0f;
        if (b == 0 && t == 0) *loss = 0.0f;
    }

    const float* relp = rel_table + (size_t)labels[b] * 1024;
    #pragma unroll
    for (int rr = 0; rr < 4; rr++) {
        const int j = w * 4 + rr;                      // row within bag
        const size_t rbase = ((size_t)b * 32 + j) * 1024;
        const float* srow = sent + rbase;
        const float* arow = aug + rbase;
        float P = 0.f, R = 0.f, A = 0.f, D = 0.f;
        #pragma unroll
        for (int i = 0; i < 4; i++) {
            const int h = i * 256 + lane * 4;
            f32x4 v  = ntld(srow + h);                 // nt: read-once
            f32x4 a  = ntld(arow + h);
            f32x4 rl = *(const f32x4*)(relp + h);      // L1-hot across rows
            P += v.x * rl.x + v.y * rl.y + v.z * rl.z + v.w * rl.w;
            R += v.x * v.x + v.y * v.y + v.z * v.z + v.w * v.w;
            A += a.x * a.x + a.y * a.y + a.z * a.z + a.w * a.w;
            D += v.x * a.x + v.y * a.y + v.z * a.z + v.w * a.w;
            bf16x4 vb = { (__bf16)v.x, (__bf16)v.y, (__bf16)v.z, (__bf16)v.w };
            *(bf16x4*)(&repS[j][h]) = vb;
            *(bf16x4*)(repb + rbase + h) = vb;
        }
        #pragma unroll
        for (int off = 32; off > 0; off >>= 1) {
            P += __shfl_xor(P, off, 64);
            R += __shfl_xor(R, off, 64);
            A += __shfl_xor(A, off, 64);
            D += __shfl_xor(D, off, 64);
        }
        if (lane == 0) {
            scoreS[j] = P * (1.0f / 32.0f);            // /sqrt(H)
            float nrv = sqrtf(R), nav = sqrtf(A);
            nr[b * 32 + j] = nrv;
            pos_sim[b * 32 + j] = D / fmaxf(nrv * nav, 1e-8f);
        }
    }
    __syncthreads();

    if (t < 32) {
        float sj = scoreS[t], mx = sj;
        #pragma unroll
        for (int off = 16; off > 0; off >>= 1) mx = fmaxf(mx, __shfl_xor(mx, off, 32));
        float e = __expf(sj - mx), sm = e;
        #pragma unroll
        for (int off = 16; off > 0; off >>= 1) sm += __shfl_xor(sm, off, 32);
        alphaS[t] = e / sm;
    }
    __syncthreads();

    float b0 = 0.f, b1 = 0.f;
    #pragma unroll 8
    for (int j = 0; j < 32; j++) {
        const float al = alphaS[j];
        bf16x2 v = *(const bf16x2*)(&repS[j][t * 2]);
        b0 += al * (float)v.x;
        b1 += al * (float)v.y;
    }
    bf16x2 bb = { (__bf16)b0, (__bf16)b1 };
    *(bf16x2*)(bagb + (size_t)b * 1024 + t * 2) = bb;

    float q = b0 * b0 + b1 * b1;
    q = wsum(q);
    if (lane == 0) redS[w] = q;
    __syncthreads();
    if (t == 0)
        nbsq[b] = redS[0] + redS[1] + redS[2] + redS[3]
                + redS[4] + redS[5] + redS[6] + redS[7];
}

// ---- k4: 128x128 tile, 4 waves of 64x64, BK=32, 3-buf counted-vmcnt pipeline ----
// Model: LDS traffic binds WHEN occupancy >= 3 waves/SIMD (r4 evidence); r5's
// 1-block/CU config proved 2 waves/SIMD can't hide latency. This config gets
// both: 64x64 waves (8KB LDS-read per 131K MAC, 2x better than 64x32) AND
// 48KB LDS -> 3 blocks/CU, 12 waves/CU. Per-CU LDS traffic 3MB (was 5MB r4).
// Buffers: 3 x 16KB (A 8KB | B 8KB), step s at smem + (s%3)*16384.
// Stage s+2 while computing s; 4 gll16/thread/step; FENCE(4) retires stage s+1
// while keeping s+2 in flight. Swizzle: slot (row,kg') holds global cols
// 8*(kg'^rho(row)), rho=(row>>1)&3; staging source pre-swizzled per-lane
// (4 lanes cover one 64B segment -> coalesced); gll16 dest linear; fragment
// reads 2-way bank = free. Classifier blocks are bid 0..7 (start first, no tail).
// Epilogue: per-wave 2-bag merge -> negp2[2][32][128] (32KB overlay, each slot
// written once) -> cross-wr-group sum -> partial[128rb][32][512] (8MB).
__global__ __launch_bounds__(256, 3) void k4_gemm(
    const __bf16* __restrict__ repb, const __bf16* __restrict__ bagb,
    const float* __restrict__ nr, const float* __restrict__ nbsq,
    const float* __restrict__ temp, float* __restrict__ partial, float* __restrict__ diag,
    const __bf16* __restrict__ cwb, const float* __restrict__ bias, float* __restrict__ out)
{
    __shared__ __align__(16) char smem[49152];         // 3 x 16KB bufs; negp2 overlays
    const int bid = blockIdx.x;
    const int t = threadIdx.x, lane = t & 63, w = t >> 6;
    const int m = lane & 15, quad = lane >> 4;

    if (bid < 8) {
        // ---- folded k3m: bag_out = bagb @ cwb^T + cls_b ----
        __bf16* Al = (__bf16*)smem;
        __bf16* Bl = (__bf16*)(smem + 8192);
        const int r0 = bid * 64;
        f32x4 acc[4] = {};
        const int i0 = t * 8;
        const int row0 = i0 >> 5, kk0 = i0 & 31;
        const __bf16* gA = bagb + (size_t)(r0 + row0) * 1024 + kk0;
        const __bf16* gB = cwb + (size_t)row0 * 1024 + kk0;
        for (int k0 = 0; k0 < 1024; k0 += 64) {
            __syncthreads();
            gll16(gA + k0,      Al + i0);
            gll16(gA + k0 + 32, Al + 2048 + i0);
            gll16(gB + k0,      Bl + i0);
            gll16(gB + k0 + 32, Bl + 2048 + i0);
            __syncthreads();
            #pragma unroll
            for (int ks = 0; ks < 2; ks++) {
                bf16x8 a = *(const bf16x8*)(&Al[ks * 2048 + (w * 16 + m) * 32 + quad * 8]);
                #pragma unroll
                for (int n = 0; n < 4; n++) {
                    bf16x8 bf = *(const bf16x8*)(&Bl[ks * 2048 + (n * 16 + m) * 32 + quad * 8]);
                    acc[n] = __builtin_amdgcn_mfma_f32_16x16x32_bf16(a, bf, acc[n], 0, 0, 0);
                }
            }
        }
        #pragma unroll
        for (int n = 0; n < 4; n++) {
            const int c = n * 16 + m;
            if (c < 53) {
                #pragma unroll
                for (int i = 0; i < 4; i++) {
                    const int r = r0 + w * 16 + quad * 4 + i;
                    out[(size_t)r * 53 + c] = acc[n][i] + bias[c];
                }
            }
        }
        return;
    }

    float* negp2 = (float*)smem;                       // [2][32][128] f32 = 32KB overlay

    const int gbid = bid - 8;
    const int xcd = gbid & 7, slot = gbid >> 3;        // slot 0..63
    const int cb = slot & 3, rb = (slot >> 2) * 8 + xcd;   // rb 0..127, cb 0..3
    const int r0 = rb * 128, c0 = cb * 128;
    const int wr0 = (w & 1) * 64, wc0 = (w >> 1) * 64;     // wave = 64x64

    // staging: thread t -> A rows {t>>2, (t>>2)+64}, B ditto (4 gll16/step)
    const int srow = t >> 2;                           // 0..63
    const int scol = 8 * ((t & 3) ^ ((srow >> 1) & 3));
    const __bf16* gA0 = repb + (size_t)(r0 + srow) * 1024 + scol;
    const __bf16* gA1 = gA0 + (size_t)64 * 1024;       // rows +64 (same swizzle)
    const __bf16* gB0 = bagb + (size_t)(c0 + srow) * 1024 + scol;
    const __bf16* gB1 = gB0 + (size_t)64 * 1024;
    const int dA0 = t * 8, dA1 = (t + 256) * 8;        // bf16 units
    const int dB0 = 4096 + t * 8, dB1 = 4096 + (t + 256) * 8;

    // fragment-read offsets (bf16 units); rho depends only on m
    const int rho = (m >> 1) & 3;
    const int offA = ((wr0 + m) * 4 + (quad ^ rho)) * 8;
    const int offB = 4096 + ((wc0 + m) * 4 + (quad ^ rho)) * 8;

    f32x4 acc[4][4] = {};

    #define BUFB(s) ((__bf16*)(smem + (((s) % 3) * 16384)))
    #define STG(s) do { const int kk_ = (s) * 32; __bf16* b_ = BUFB(s);     \
        gll16(gA0 + kk_, b_ + dA0); gll16(gA1 + kk_, b_ + dA1);             \
        gll16(gB0 + kk_, b_ + dB0); gll16(gB1 + kk_, b_ + dB1); } while (0)

    #define CMP(s) do { const __bf16* b_ = BUFB(s); bf16x8 av_[4], bv_[4];  \
        _Pragma("unroll") for (int i_ = 0; i_ < 4; i_++)                    \
            av_[i_] = *(const bf16x8*)(b_ + offA + i_ * 512);               \
        _Pragma("unroll") for (int n_ = 0; n_ < 4; n_++)                    \
            bv_[n_] = *(const bf16x8*)(b_ + offB + n_ * 512);               \
        _Pragma("unroll") for (int i_ = 0; i_ < 4; i_++)                    \
        _Pragma("unroll") for (int n_ = 0; n_ < 4; n_++)                    \
            acc[i_][n_] = __builtin_amdgcn_mfma_f32_16x16x32_bf16(          \
                av_[i_], bv_[n_], acc[i_][n_], 0, 0, 0); } while (0)

    #define FENCE(N) do { __builtin_amdgcn_sched_barrier(0);                \
        asm volatile("s_waitcnt vmcnt(" #N ")" ::: "memory");               \
        __builtin_amdgcn_s_barrier();                                       \
        __builtin_amdgcn_sched_barrier(0); } while (0)

    STG(0); STG(1);
    FENCE(4);                                   // step 0 resident; 1 in flight
    #pragma unroll 1
    for (int s = 0; s < 30; ++s) {              // stage s+2, compute s
        STG(s + 2);
        CMP(s);
        FENCE(4);                               // retire s+1; keep s+2 flying
    }
    CMP(30); FENCE(0);                          // retire step 31
    CMP(31);
    __syncthreads();                            // all buf reads done -> negp2 safe

    const float invT = 1.0f / *temp;
    float nrv[16];
    #pragma unroll
    for (int i = 0; i < 4; i++)
        #pragma unroll
        for (int g = 0; g < 4; g++)
            nrv[i * 4 + g] = nr[r0 + wr0 + i * 16 + quad * 4 + g];

    // per-wave 2-bag merge into negp2[wr0/64][jj][c_local]; each slot written once
    float* myneg = negp2 + (size_t)(w & 1) * 32 * 128;
    #pragma unroll
    for (int n = 0; n < 4; n++) {
        const int c_local = wc0 + n * 16 + m;
        const int cg = c0 + c_local;
        const float nbv = sqrtf(nbsq[cg]);
        #pragma unroll
        for (int i = 0; i < 2; i++) {                  // bag pairs (i, i+2): same j
            #pragma unroll
            for (int g = 0; g < 4; g++) {
                const int jj = i * 16 + quad * 4 + g;
                const int rg0 = r0 + wr0 + i * 16 + quad * 4 + g;
                const int rg2 = rg0 + 32;
                float e0 = __expf(acc[i][n][g]     / fmaxf(nbv * nrv[i * 4 + g],       1e-8f) * invT);
                float e2 = __expf(acc[i + 2][n][g] / fmaxf(nbv * nrv[(i + 2) * 4 + g], 1e-8f) * invT);
                myneg[jj * 128 + c_local] = e0 + e2;
                if ((rg0 >> 5) == cg) diag[(size_t)cg * 32 + jj] = e0;
                if ((rg2 >> 5) == cg) diag[(size_t)cg * 32 + jj] = e2;
            }
        }
    }
    __syncthreads();

    // cross-wr-group reduce + write partial[rb][jj][c0..c0+127]
    float* pout = partial + (size_t)rb * 32 * 512 + c0;
    {
        const int jj = t >> 3, c16 = (t & 7) * 16;     // 256 thr x 16 = 4096 outs
        #pragma unroll
        for (int v = 0; v < 4; v++) {
            f32x4 a = *(const f32x4*)(negp2 + jj * 128 + c16 + v * 4);
            f32x4 bq = *(const f32x4*)(negp2 + 32 * 128 + jj * 128 + c16 + v * 4);
            *(f32x4*)(pout + (size_t)jj * 512 + c16 + v * 4) = a + bq;
        }
    }
    #undef BUFB
    #undef STG
    #undef CMP
    #undef FENCE
}

// ---- k5: reduce partial over rb (128) + loss terms; atomic accumulate into loss ----
__global__ __launch_bounds__(256) void k5_neg(
    const float* __restrict__ partial, const float* __restrict__ diag,
    const float* __restrict__ pos_sim, const float* __restrict__ temp,
    float* __restrict__ loss)
{
    const int ct = blockIdx.x & 7, j = blockIdx.x >> 3;
    const int t = threadIdx.x, lane = t & 63, w = t >> 6;
    const int bsub = t >> 4;                           // 0..15 (rb-group of 8)
    const int cidx = t & 15;                           // x4 cols
    f32x4 acc = {};
    #pragma unroll 4
    for (int r = 0; r < 8; r++) {
        const int rb = bsub * 8 + r;
        f32x4 v = *(const f32x4*)(partial + ((size_t)rb * 32 + j) * 512 + ct * 64 + cidx * 4);
        acc += v;
    }
    #pragma unroll
    for (int k = 0; k < 4; k++) {
        acc[k] += __shfl_xor(acc[k], 16, 64);
        acc[k] += __shfl_xor(acc[k], 32, 64);
    }
    __shared__ float red[4][64];
    if (lane < 16) {
        #pragma unroll
        for (int k = 0; k < 4; k++) red[w][lane * 4 + k] = acc[k];
    }
    __syncthreads();

    if (t < 64) {
        const int c = ct * 64 + t;
        float S = red[0][t] + red[1][t] + red[2][t] + red[3][t];
        S -= diag[(size_t)c * 32 + j];                 // near-exact cancellation (f32)
        const float invT = 1.0f / *temp;
        const float lp = pos_sim[(c << 5) + j] * invT;
        float term = logf(__expf(lp) + S) - lp;
        term = wsum(term);
        if (t == 0) atomicAdd(loss, term * (1.0f / 16384.0f));
    }
}

extern "C" void kernel_launch(void* const* d_in, const int* in_sizes, int n_in,
                              void* d_out, int out_size, void* d_ws, size_t ws_size,
                              hipStream_t stream)
{
    const float* sent = (const float*)d_in[0];
    const float* aug  = (const float*)d_in[1];
    const float* rel  = (const float*)d_in[2];
    const float* clsw = (const float*)d_in[3];
    const float* clsb = (const float*)d_in[4];
    const int*   lab  = (const int*)d_in[5];
    const float* temp = (const float*)d_in[6];
    float* out = (float*)d_out;

    char* ws = (char*)d_ws;
    __bf16* bagb    = (__bf16*)(ws);                           // 1 MB
    float*  nbsq    = (float*)(ws + (1u << 20));               // 2 KB
    float*  nr      = (float*)(ws + (1u << 20) + 64 * 1024);   // 64 KB
    float*  pos     = (float*)(ws + (1u << 20) + 128 * 1024);  // 64 KB
    __bf16* cwb     = (__bf16*)(ws + (1u << 20) + 192 * 1024); // 128 KB
    float*  diag    = (float*)(ws + (2u << 20) + 64 * 1024);   // 64 KB
    __bf16* repb    = (__bf16*)(ws + (4u << 20));              // 32 MB
    float*  partial = (float*)(ws + (36u << 20));              // 8 MB (128 rb)

    float* loss = out + 27136;

    kab    <<<512, 512, 0, stream>>>(sent, aug, rel, lab, repb, nr, pos,
                                     clsw, cwb, bagb, nbsq, loss);
    k4_gemm<<<520, 256, 0, stream>>>(repb, bagb, nr, nbsq, temp, partial, diag,
                                     cwb, clsb, out);
    k5_neg <<<256, 256, 0, stream>>>(partial, diag, pos, temp, loss);
}